// Round 11
// baseline (376.423 us; speedup 1.0000x reference)
//
#include <hip/hip_runtime.h>

typedef __attribute__((ext_vector_type(4)))  float   floatx4;
typedef __attribute__((ext_vector_type(16))) float   floatx16;
typedef __attribute__((ext_vector_type(8)))  __bf16  bf16x8;
typedef unsigned short ushort_t;
typedef __attribute__((ext_vector_type(8)))  ushort_t ushortx8;

typedef const unsigned int __attribute__((address_space(1)))* gptr_t;
typedef unsigned int __attribute__((address_space(3)))* lptr_t;

#define NIMG 32
#define H    112
#define W    112
#define CIN  128
#define COUT 256
#define HP   114
#define WP   114
#define HW   12544      // H*W, = 49*256 so every 256-row tile stays in one image

#define BM 256
#define BN 256
#define BK 64
#define NT 18           // K = 3*3*128 = 1152 = 18*64

#define PREPAD_BLOCKS 12996   // 32*114*114*8 / 256  (32B per thread)
#define WTRANS_BLOCKS 1152    // 3*3*256*128 / 256

// ---------- fp32 -> bf16 (round-to-nearest-even) ----------
__device__ __forceinline__ ushort_t f32_to_bf16(float f) {
    unsigned u = __float_as_uint(f);
    unsigned r = 0x7fffu + ((u >> 16) & 1u);
    return (ushort_t)((u + r) >> 16);
}

// ---------- Fused prepass (r8-verified, unchanged) ----------
__global__ __launch_bounds__(256) void prepass_fused(const float* __restrict__ in,
                                                     const float* __restrict__ k,
                                                     ushort_t* __restrict__ pad,
                                                     ushort_t* __restrict__ wt) {
    int bid = blockIdx.x;
    if (bid < PREPAD_BLOCKS) {
        int u    = bid * 256 + threadIdx.x;
        int ic16 = u & 7;
        int sp   = u >> 3;
        int iw   = sp % WP;
        int sp2  = sp / WP;
        int ih   = sp2 % HP;
        int n    = sp2 / HP;
        ushortx8 v0, v1;
        if (ih >= 1 && ih <= H && iw >= 1 && iw <= W) {
            const float* src = in + ((size_t)((n * H + (ih - 1)) * W + (iw - 1))) * CIN + ic16 * 16;
            floatx4 a = *reinterpret_cast<const floatx4*>(src);
            floatx4 b = *reinterpret_cast<const floatx4*>(src + 4);
            floatx4 c = *reinterpret_cast<const floatx4*>(src + 8);
            floatx4 d = *reinterpret_cast<const floatx4*>(src + 12);
#pragma unroll
            for (int j = 0; j < 4; ++j) {
                v0[j] = f32_to_bf16(a[j]); v0[4 + j] = f32_to_bf16(b[j]);
                v1[j] = f32_to_bf16(c[j]); v1[4 + j] = f32_to_bf16(d[j]);
            }
        } else {
#pragma unroll
            for (int j = 0; j < 8; ++j) { v0[j] = 0; v1[j] = 0; }
        }
        ushortx8* dst = reinterpret_cast<ushortx8*>(pad) + ((size_t)sp * 16 + ic16 * 2);
        dst[0] = v0;
        dst[1] = v1;
    } else {
        int t    = (bid - PREPAD_BLOCKS) * 256 + threadIdx.x;
        int ic   = t & 127;
        int oc   = (t >> 7) & 255;
        int khkw = t >> 15;
        wt[t] = f32_to_bf16(k[((size_t)(khkw * CIN + ic)) * COUT + oc]);
    }
}

// ---------- K-tile global offsets ----------
__device__ __forceinline__ int aoffK(int t) {
    int tap = t >> 1;
    return ((tap / 3) * WP + (tap % 3)) * CIN + (t & 1) * 64;
}
__device__ __forceinline__ int boffK(int t) {
    int tap = t >> 1;
    return tap * (COUT * CIN) + (t & 1) * 64;
}

// ---------- Main: 256x256 8-phase, single-buffered LDS, 32x32x16 MFMA ----------
// r10 base (PASSING) with ONE change: MFMA shape 16x16x32 -> 32x32x16 (measured
// ceiling 2382 vs 2075 TF; halves MFMA instruction count). Schedule-isomorphic:
// phase q consumes exactly A-chunk-q rows (32q..32q+32 per 128-half) under both
// shapes, so staging / single-buffer lifetimes / vmcnt ledger / barriers are
// byte-identical to r10. Per phase: 1 rowblock x 2 colblocks x 4 kslices = 8 MFMA.
// Fragment maps: A/B operand lane->elem: row(col)=lane&31, k=(lane>>5)*8+j;
// C/D (HW-verified m74/m101): col=lane&31, row=(reg&3)+8*(reg>>2)+4*(lane>>5).
// Swizzle read addr: chunk = (ksl*2 + (lane>>5)) ^ (row&7), row&7 == lane&7.

__global__ __launch_bounds__(512, 2) void conv_mfma8(const ushort_t* __restrict__ pad,
                                                     const ushort_t* __restrict__ wt,
                                                     const float* __restrict__ bias,
                                                     float* __restrict__ out) {
    __shared__ __align__(16) ushort_t lds[32768];   // 64 KiB: A[256][64] @0, B[256][64] @16384

    const int tid  = threadIdx.x;
    const int wid  = tid >> 6;
    const int lane = tid & 63;
    const int wm   = wid >> 2;       // 0..1 : 128-row band
    const int wn   = wid & 3;        // 0..3 : 64-col band
    const int bid  = blockIdx.x;
    const int bm   = (bid & 7) * 196 + (bid >> 3);   // XCD swizzle, 1568 % 8 == 0

    // ---- A-chunk staging geometry (identical to r10) ----
    const int rb   = (tid & 255) >> 3;
    const int half = tid >> 8;
    const int lc   = (tid & 7) ^ (rb & 7);

    const ushort_t* srcAc[4];
#pragma unroll
    for (int q = 0; q < 4; ++q) {
        int m  = bm * BM + half * 128 + q * 32 + rb;
        int n  = m / HW;
        int r  = m % HW;
        int oh = r / W;
        int ow = r % W;
        srcAc[q] = pad + ((size_t)((n * HP + oh) * WP + ow)) * CIN + lc * 8;
    }
    const ushort_t* srcB[4];
#pragma unroll
    for (int i = 0; i < 4; ++i)
        srcB[i] = wt + (size_t)(i * 64 + ((tid >> 3) & 63)) * CIN
                     + (((tid & 7) ^ ((tid >> 3) & 7)) * 8);

    const int awBase   = (wid >> 2) * 8192 + (wid & 3) * 512;
    const int dstSlotB = wid * 512;

#define STAGE_AC(q_, oA)                                                                            \
    __builtin_amdgcn_global_load_lds((gptr_t)(srcAc[q_] + (oA)),                                    \
                                     (lptr_t)&lds[(q_) * 2048 + awBase], 16, 0, 0);
#define STAGE_B1(j_, oB)                                                                            \
    __builtin_amdgcn_global_load_lds((gptr_t)(srcB[j_] + (oB)),                                     \
                                     (lptr_t)&lds[16384 + (j_) * 4096 + dstSlotB], 16, 0, 0);

    // ---- read-side constants (32x32 fragments) ----
    const int aBase = (wm * 128 + (lane & 31)) * 64;            // + q*2048 per phase
    const int bBase = 16384 + (wn * 64 + (lane & 31)) * 64;     // + cb*2048 per colblock
    int cOff[4];
#pragma unroll
    for (int ksl = 0; ksl < 4; ++ksl)
        cOff[ksl] = ((ksl * 2 + (lane >> 5)) ^ (lane & 7)) * 8;

    floatx16 acc[4][2];
#pragma unroll
    for (int i = 0; i < 4; ++i)
#pragma unroll
        for (int j = 0; j < 2; ++j) acc[i][j] = (floatx16)0.0f;

    // ---- prologue: A(0) chunks 0-2 + B(0) slices 0-3; full drain (once) ----
    {
        const int oA0 = aoffK(0);
        const int oB0 = boffK(0);
        STAGE_AC(0, oA0); STAGE_AC(1, oA0); STAGE_AC(2, oA0);
        STAGE_B1(0, oB0); STAGE_B1(1, oB0); STAGE_B1(2, oB0); STAGE_B1(3, oB0);
    }
    asm volatile("s_waitcnt vmcnt(0)" ::: "memory");
    __builtin_amdgcn_s_barrier();

    // ---- main loop (r10 schedule verbatim; only frag reads + MFMA shape differ) ----
    for (int t = 0; t < NT; ++t) {
        const int oAc = aoffK(t);
        const int oAn = aoffK(t + 1);
        const int oBn = boffK(t + 1);
        bf16x8 bfr[2][4];
#pragma unroll
        for (int q = 0; q < 4; ++q) {
            bf16x8 af[4];
#pragma unroll
            for (int ksl = 0; ksl < 4; ++ksl)
                af[ksl] = *reinterpret_cast<const bf16x8*>(&lds[aBase + q * 2048 + cOff[ksl]]);
            if (q == 0) {
#pragma unroll
                for (int ksl = 0; ksl < 4; ++ksl)   // cb=0 pre-barrier; cb=1 deferred
                    bfr[0][ksl] = *reinterpret_cast<const bf16x8*>(&lds[bBase + cOff[ksl]]);
            }
            // staging issues (after the barrier that retired the region's reads)
            if (q == 0) { STAGE_AC(3, oAc); }
            if (q == 1 && t + 1 < NT) { STAGE_AC(0, oAn); STAGE_B1(0, oBn); STAGE_B1(1, oBn); }
            if (q == 2 && t + 1 < NT) { STAGE_AC(1, oAn); STAGE_B1(2, oBn); STAGE_B1(3, oBn); }
            if (q == 3 && t + 1 < NT) { STAGE_AC(2, oAn); }
            __builtin_amdgcn_s_barrier();
            __builtin_amdgcn_s_setprio(1);
            if (q == 0) {
#pragma unroll
                for (int ksl = 0; ksl < 4; ++ksl)
                    acc[0][0] = __builtin_amdgcn_mfma_f32_32x32x16_bf16(af[ksl], bfr[0][ksl], acc[0][0], 0, 0, 0);
#pragma unroll
                for (int ksl = 0; ksl < 4; ++ksl)   // deferred cb=1 reads (q0-burst smoothing)
                    bfr[1][ksl] = *reinterpret_cast<const bf16x8*>(&lds[bBase + 2048 + cOff[ksl]]);
#pragma unroll
                for (int ksl = 0; ksl < 4; ++ksl)
                    acc[0][1] = __builtin_amdgcn_mfma_f32_32x32x16_bf16(af[ksl], bfr[1][ksl], acc[0][1], 0, 0, 0);
            } else {
#pragma unroll
                for (int ksl = 0; ksl < 4; ++ksl) {
                    acc[q][0] = __builtin_amdgcn_mfma_f32_32x32x16_bf16(af[ksl], bfr[0][ksl], acc[q][0], 0, 0, 0);
                    acc[q][1] = __builtin_amdgcn_mfma_f32_32x32x16_bf16(af[ksl], bfr[1][ksl], acc[q][1], 0, 0, 0);
                }
            }
            __builtin_amdgcn_s_setprio(0);
            // counted waits (r10 FIFO ledger, unchanged)
            if (q == 1) {
                if (t < NT - 1) { asm volatile("s_waitcnt vmcnt(4)" ::: "memory"); }
                else            { asm volatile("s_waitcnt vmcnt(1)" ::: "memory"); }
            }
            if (q == 2) {
                if (t < NT - 1) { asm volatile("s_waitcnt vmcnt(6)" ::: "memory"); }
                else            { asm volatile("s_waitcnt vmcnt(0)" ::: "memory"); }
            }
            if (q == 3) { asm volatile("s_waitcnt vmcnt(1)" ::: "memory"); }
            __builtin_amdgcn_s_barrier();
        }
    }

    // ---- epilogue: 32x32 C/D map col=lane&31, row=(reg&3)+8*(reg>>2)+4*(lane>>5) ----
    const int colL = wn * 64 + (lane & 31);
    const int rowL = bm * BM + wm * 128 + 4 * (lane >> 5);
    float bv[2];
#pragma unroll
    for (int cb = 0; cb < 2; ++cb) bv[cb] = bias[colL + cb * 32];
#pragma unroll
    for (int q = 0; q < 4; ++q)
#pragma unroll
        for (int cb = 0; cb < 2; ++cb)
#pragma unroll
            for (int reg = 0; reg < 16; ++reg) {
                int row = rowL + q * 32 + (reg & 3) + 8 * (reg >> 2);
                out[(size_t)row * COUT + colL + cb * 32] = acc[q][cb][reg] + bv[cb];
            }
#undef STAGE_AC
#undef STAGE_B1
}

extern "C" void kernel_launch(void* const* d_in, const int* in_sizes, int n_in,
                              void* d_out, int out_size, void* d_ws, size_t ws_size,
                              hipStream_t stream) {
    const float* input = (const float*)d_in[0];
    const float* kern  = (const float*)d_in[1];
    const float* bias  = (const float*)d_in[2];
    float* out         = (float*)d_out;

    ushort_t* pad = (ushort_t*)d_ws;                          // 106,463,232 B
    ushort_t* wt  = pad + (size_t)NIMG * HP * WP * CIN;       // + 589,824 B

    prepass_fused<<<PREPAD_BLOCKS + WTRANS_BLOCKS, 256, 0, stream>>>(input, kern, pad, wt);
    conv_mfma8<<<1568, 512, 0, stream>>>(pad, wt, bias, out); // 1568 = 401408/256, %8==0
}

// Round 12
// 362.632 us; speedup vs baseline: 1.0380x; 1.0380x over previous
//
#include <hip/hip_runtime.h>

typedef __attribute__((ext_vector_type(4)))  float   floatx4;
typedef __attribute__((ext_vector_type(16))) float   floatx16;
typedef __attribute__((ext_vector_type(8)))  __bf16  bf16x8;
typedef unsigned short ushort_t;
typedef __attribute__((ext_vector_type(8)))  ushort_t ushortx8;

typedef const unsigned int __attribute__((address_space(1)))* gptr_t;
typedef unsigned int __attribute__((address_space(3)))* lptr_t;

#define NIMG 32
#define H    112
#define W    112
#define CIN  128
#define COUT 256
#define HP   114
#define WP   114
#define HW   12544      // H*W, = 49*256 so every 256-row tile stays in one image

#define BM 256
#define BN 256
#define BK 64
#define NT 18           // K = 3*3*128 = 1152 = 18*64

#define PREPAD_BLOCKS 12996   // 32*114*114*8 / 256  (32B per thread)
#define WTRANS_BLOCKS 1152    // 3*3*256*128 / 256

// ---------- fp32 -> bf16 (round-to-nearest-even) ----------
__device__ __forceinline__ ushort_t f32_to_bf16(float f) {
    unsigned u = __float_as_uint(f);
    unsigned r = 0x7fffu + ((u >> 16) & 1u);
    return (ushort_t)((u + r) >> 16);
}

// ---------- Fused prepass (r8-verified, unchanged) ----------
__global__ __launch_bounds__(256) void prepass_fused(const float* __restrict__ in,
                                                     const float* __restrict__ k,
                                                     ushort_t* __restrict__ pad,
                                                     ushort_t* __restrict__ wt) {
    int bid = blockIdx.x;
    if (bid < PREPAD_BLOCKS) {
        int u    = bid * 256 + threadIdx.x;
        int ic16 = u & 7;
        int sp   = u >> 3;
        int iw   = sp % WP;
        int sp2  = sp / WP;
        int ih   = sp2 % HP;
        int n    = sp2 / HP;
        ushortx8 v0, v1;
        if (ih >= 1 && ih <= H && iw >= 1 && iw <= W) {
            const float* src = in + ((size_t)((n * H + (ih - 1)) * W + (iw - 1))) * CIN + ic16 * 16;
            floatx4 a = *reinterpret_cast<const floatx4*>(src);
            floatx4 b = *reinterpret_cast<const floatx4*>(src + 4);
            floatx4 c = *reinterpret_cast<const floatx4*>(src + 8);
            floatx4 d = *reinterpret_cast<const floatx4*>(src + 12);
#pragma unroll
            for (int j = 0; j < 4; ++j) {
                v0[j] = f32_to_bf16(a[j]); v0[4 + j] = f32_to_bf16(b[j]);
                v1[j] = f32_to_bf16(c[j]); v1[4 + j] = f32_to_bf16(d[j]);
            }
        } else {
#pragma unroll
            for (int j = 0; j < 8; ++j) { v0[j] = 0; v1[j] = 0; }
        }
        ushortx8* dst = reinterpret_cast<ushortx8*>(pad) + ((size_t)sp * 16 + ic16 * 2);
        dst[0] = v0;
        dst[1] = v1;
    } else {
        int t    = (bid - PREPAD_BLOCKS) * 256 + threadIdx.x;
        int ic   = t & 127;
        int oc   = (t >> 7) & 255;
        int khkw = t >> 15;
        wt[t] = f32_to_bf16(k[((size_t)(khkw * CIN + ic)) * COUT + oc]);
    }
}

// ---------- K-tile global offsets ----------
__device__ __forceinline__ int aoffK(int t) {
    int tap = t >> 1;
    return ((tap / 3) * WP + (tap % 3)) * CIN + (t & 1) * 64;
}
__device__ __forceinline__ int boffK(int t) {
    int tap = t >> 1;
    return tap * (COUT * CIN) + (t & 1) * 64;
}

// ---------- Main: 256x256 8-phase, single-buffered LDS, 32x32x16 MFMA ----------
// r11 with ONE change: storage/read swizzle strengthened from g(r)=r&7 to
// g(r) = (r&7) ^ ((r>>3)&3). r11's 2.17e7 bank conflicts came from the 32x32
// operand layout's k-selector (lane>>5): within a 16-lane read group the chunk
// (ksl*2+hi)^(lane&7) left lanes {l,l+8,l+16,l+24} of each 32-lane half on one
// chunk column (4-way). XOR-ing row bits 3-4 into the chunk restores the
// 16x16-verified property: 8 distinct chunks x2 per 16-lane group (2-way=free).
// Applied BOTH sides: staging source lc = (tid&7) ^ g(row), read
// cOff = ((ksl*2+hi) ^ g(lane&31))*8. All staging/read row bases 32-aligned.
// Everything else (schedule, ledger, maps) byte-identical to r11.

__global__ __launch_bounds__(512, 2) void conv_mfma8(const ushort_t* __restrict__ pad,
                                                     const ushort_t* __restrict__ wt,
                                                     const float* __restrict__ bias,
                                                     float* __restrict__ out) {
    __shared__ __align__(16) ushort_t lds[32768];   // 64 KiB: A[256][64] @0, B[256][64] @16384

    const int tid  = threadIdx.x;
    const int wid  = tid >> 6;
    const int lane = tid & 63;
    const int wm   = wid >> 2;       // 0..1 : 128-row band
    const int wn   = wid & 3;        // 0..3 : 64-col band
    const int bid  = blockIdx.x;
    const int bm   = (bid & 7) * 196 + (bid >> 3);   // XCD swizzle, 1568 % 8 == 0

    // ---- A-chunk staging geometry ----
    const int rb   = (tid & 255) >> 3;
    const int half = tid >> 8;
    const int lc   = (tid & 7) ^ (rb & 7) ^ ((rb >> 3) & 3);   // g(rb)

    const ushort_t* srcAc[4];
#pragma unroll
    for (int q = 0; q < 4; ++q) {
        int m  = bm * BM + half * 128 + q * 32 + rb;
        int n  = m / HW;
        int r  = m % HW;
        int oh = r / W;
        int ow = r % W;
        srcAc[q] = pad + ((size_t)((n * HP + oh) * WP + ow)) * CIN + lc * 8;
    }
    const ushort_t* srcB[4];
#pragma unroll
    for (int i = 0; i < 4; ++i)
        srcB[i] = wt + (size_t)(i * 64 + ((tid >> 3) & 63)) * CIN
                     + ((((tid & 7) ^ ((tid >> 3) & 7) ^ ((tid >> 6) & 3))) * 8);  // g(rw&31)

    const int awBase   = (wid >> 2) * 8192 + (wid & 3) * 512;
    const int dstSlotB = wid * 512;

#define STAGE_AC(q_, oA)                                                                            \
    __builtin_amdgcn_global_load_lds((gptr_t)(srcAc[q_] + (oA)),                                    \
                                     (lptr_t)&lds[(q_) * 2048 + awBase], 16, 0, 0);
#define STAGE_B1(j_, oB)                                                                            \
    __builtin_amdgcn_global_load_lds((gptr_t)(srcB[j_] + (oB)),                                     \
                                     (lptr_t)&lds[16384 + (j_) * 4096 + dstSlotB], 16, 0, 0);

    // ---- read-side constants (32x32 fragments; g-swizzled) ----
    const int aBase = (wm * 128 + (lane & 31)) * 64;            // + q*2048 per phase
    const int bBase = 16384 + (wn * 64 + (lane & 31)) * 64;     // + cb*2048 per colblock
    const int gr    = (lane & 7) ^ ((lane >> 3) & 3);           // g(lane&31)
    int cOff[4];
#pragma unroll
    for (int ksl = 0; ksl < 4; ++ksl)
        cOff[ksl] = ((ksl * 2 + (lane >> 5)) ^ gr) * 8;

    floatx16 acc[4][2];
#pragma unroll
    for (int i = 0; i < 4; ++i)
#pragma unroll
        for (int j = 0; j < 2; ++j) acc[i][j] = (floatx16)0.0f;

    // ---- prologue: A(0) chunks 0-2 + B(0) slices 0-3; full drain (once) ----
    {
        const int oA0 = aoffK(0);
        const int oB0 = boffK(0);
        STAGE_AC(0, oA0); STAGE_AC(1, oA0); STAGE_AC(2, oA0);
        STAGE_B1(0, oB0); STAGE_B1(1, oB0); STAGE_B1(2, oB0); STAGE_B1(3, oB0);
    }
    asm volatile("s_waitcnt vmcnt(0)" ::: "memory");
    __builtin_amdgcn_s_barrier();

    // ---- main loop (r10/r11 schedule verbatim) ----
    for (int t = 0; t < NT; ++t) {
        const int oAc = aoffK(t);
        const int oAn = aoffK(t + 1);
        const int oBn = boffK(t + 1);
        bf16x8 bfr[2][4];
#pragma unroll
        for (int q = 0; q < 4; ++q) {
            bf16x8 af[4];
#pragma unroll
            for (int ksl = 0; ksl < 4; ++ksl)
                af[ksl] = *reinterpret_cast<const bf16x8*>(&lds[aBase + q * 2048 + cOff[ksl]]);
            if (q == 0) {
#pragma unroll
                for (int ksl = 0; ksl < 4; ++ksl)   // cb=0 pre-barrier; cb=1 deferred
                    bfr[0][ksl] = *reinterpret_cast<const bf16x8*>(&lds[bBase + cOff[ksl]]);
            }
            // staging issues (after the barrier that retired the region's reads)
            if (q == 0) { STAGE_AC(3, oAc); }
            if (q == 1 && t + 1 < NT) { STAGE_AC(0, oAn); STAGE_B1(0, oBn); STAGE_B1(1, oBn); }
            if (q == 2 && t + 1 < NT) { STAGE_AC(1, oAn); STAGE_B1(2, oBn); STAGE_B1(3, oBn); }
            if (q == 3 && t + 1 < NT) { STAGE_AC(2, oAn); }
            __builtin_amdgcn_s_barrier();
            __builtin_amdgcn_s_setprio(1);
            if (q == 0) {
#pragma unroll
                for (int ksl = 0; ksl < 4; ++ksl)
                    acc[0][0] = __builtin_amdgcn_mfma_f32_32x32x16_bf16(af[ksl], bfr[0][ksl], acc[0][0], 0, 0, 0);
#pragma unroll
                for (int ksl = 0; ksl < 4; ++ksl)   // deferred cb=1 reads (q0-burst smoothing)
                    bfr[1][ksl] = *reinterpret_cast<const bf16x8*>(&lds[bBase + 2048 + cOff[ksl]]);
#pragma unroll
                for (int ksl = 0; ksl < 4; ++ksl)
                    acc[0][1] = __builtin_amdgcn_mfma_f32_32x32x16_bf16(af[ksl], bfr[1][ksl], acc[0][1], 0, 0, 0);
            } else {
#pragma unroll
                for (int ksl = 0; ksl < 4; ++ksl) {
                    acc[q][0] = __builtin_amdgcn_mfma_f32_32x32x16_bf16(af[ksl], bfr[0][ksl], acc[q][0], 0, 0, 0);
                    acc[q][1] = __builtin_amdgcn_mfma_f32_32x32x16_bf16(af[ksl], bfr[1][ksl], acc[q][1], 0, 0, 0);
                }
            }
            __builtin_amdgcn_s_setprio(0);
            // counted waits (r10 FIFO ledger, unchanged)
            if (q == 1) {
                if (t < NT - 1) { asm volatile("s_waitcnt vmcnt(4)" ::: "memory"); }
                else            { asm volatile("s_waitcnt vmcnt(1)" ::: "memory"); }
            }
            if (q == 2) {
                if (t < NT - 1) { asm volatile("s_waitcnt vmcnt(6)" ::: "memory"); }
                else            { asm volatile("s_waitcnt vmcnt(0)" ::: "memory"); }
            }
            if (q == 3) { asm volatile("s_waitcnt vmcnt(1)" ::: "memory"); }
            __builtin_amdgcn_s_barrier();
        }
    }

    // ---- epilogue: 32x32 C/D map col=lane&31, row=(reg&3)+8*(reg>>2)+4*(lane>>5) ----
    const int colL = wn * 64 + (lane & 31);
    const int rowL = bm * BM + wm * 128 + 4 * (lane >> 5);
    float bv[2];
#pragma unroll
    for (int cb = 0; cb < 2; ++cb) bv[cb] = bias[colL + cb * 32];
#pragma unroll
    for (int q = 0; q < 4; ++q)
#pragma unroll
        for (int cb = 0; cb < 2; ++cb)
#pragma unroll
            for (int reg = 0; reg < 16; ++reg) {
                int row = rowL + q * 32 + (reg & 3) + 8 * (reg >> 2);
                out[(size_t)row * COUT + colL + cb * 32] = acc[q][cb][reg] + bv[cb];
            }
#undef STAGE_AC
#undef STAGE_B1
}

extern "C" void kernel_launch(void* const* d_in, const int* in_sizes, int n_in,
                              void* d_out, int out_size, void* d_ws, size_t ws_size,
                              hipStream_t stream) {
    const float* input = (const float*)d_in[0];
    const float* kern  = (const float*)d_in[1];
    const float* bias  = (const float*)d_in[2];
    float* out         = (float*)d_out;

    ushort_t* pad = (ushort_t*)d_ws;                          // 106,463,232 B
    ushort_t* wt  = pad + (size_t)NIMG * HP * WP * CIN;       // + 589,824 B

    prepass_fused<<<PREPAD_BLOCKS + WTRANS_BLOCKS, 256, 0, stream>>>(input, kern, pad, wt);
    conv_mfma8<<<1568, 512, 0, stream>>>(pad, wt, bias, out); // 1568 = 401408/256, %8==0
}

// Round 13
// 349.607 us; speedup vs baseline: 1.0767x; 1.0373x over previous
//
#include <hip/hip_runtime.h>

typedef __attribute__((ext_vector_type(4)))  float   floatx4;
typedef __attribute__((ext_vector_type(16))) float   floatx16;
typedef __attribute__((ext_vector_type(8)))  __bf16  bf16x8;
typedef unsigned short ushort_t;
typedef __attribute__((ext_vector_type(8)))  ushort_t ushortx8;

typedef const unsigned int __attribute__((address_space(1)))* gptr_t;
typedef unsigned int __attribute__((address_space(3)))* lptr_t;

#define NIMG 32
#define H    112
#define W    112
#define CIN  128
#define COUT 256
#define HP   114
#define WP   114
#define HW   12544      // H*W, = 49*256 so every 256-row tile stays in one image

#define BM 256
#define BN 256
#define BK 64
#define NT 18           // K = 3*3*128 = 1152 = 18*64

#define PREPAD_BLOCKS 12996   // 32*114*114*8 / 256  (32B per thread)
#define WTRANS_BLOCKS 1152    // 3*3*256*128 / 256

// ---------- fp32 -> bf16 (round-to-nearest-even) ----------
__device__ __forceinline__ ushort_t f32_to_bf16(float f) {
    unsigned u = __float_as_uint(f);
    unsigned r = 0x7fffu + ((u >> 16) & 1u);
    return (ushort_t)((u + r) >> 16);
}

// ---------- Fused prepass (r8-verified, unchanged) ----------
__global__ __launch_bounds__(256) void prepass_fused(const float* __restrict__ in,
                                                     const float* __restrict__ k,
                                                     ushort_t* __restrict__ pad,
                                                     ushort_t* __restrict__ wt) {
    int bid = blockIdx.x;
    if (bid < PREPAD_BLOCKS) {
        int u    = bid * 256 + threadIdx.x;
        int ic16 = u & 7;
        int sp   = u >> 3;
        int iw   = sp % WP;
        int sp2  = sp / WP;
        int ih   = sp2 % HP;
        int n    = sp2 / HP;
        ushortx8 v0, v1;
        if (ih >= 1 && ih <= H && iw >= 1 && iw <= W) {
            const float* src = in + ((size_t)((n * H + (ih - 1)) * W + (iw - 1))) * CIN + ic16 * 16;
            floatx4 a = *reinterpret_cast<const floatx4*>(src);
            floatx4 b = *reinterpret_cast<const floatx4*>(src + 4);
            floatx4 c = *reinterpret_cast<const floatx4*>(src + 8);
            floatx4 d = *reinterpret_cast<const floatx4*>(src + 12);
#pragma unroll
            for (int j = 0; j < 4; ++j) {
                v0[j] = f32_to_bf16(a[j]); v0[4 + j] = f32_to_bf16(b[j]);
                v1[j] = f32_to_bf16(c[j]); v1[4 + j] = f32_to_bf16(d[j]);
            }
        } else {
#pragma unroll
            for (int j = 0; j < 8; ++j) { v0[j] = 0; v1[j] = 0; }
        }
        ushortx8* dst = reinterpret_cast<ushortx8*>(pad) + ((size_t)sp * 16 + ic16 * 2);
        dst[0] = v0;
        dst[1] = v1;
    } else {
        int t    = (bid - PREPAD_BLOCKS) * 256 + threadIdx.x;
        int ic   = t & 127;
        int oc   = (t >> 7) & 255;
        int khkw = t >> 15;
        wt[t] = f32_to_bf16(k[((size_t)(khkw * CIN + ic)) * COUT + oc]);
    }
}

// ---------- K-tile global offsets ----------
__device__ __forceinline__ int aoffK(int t) {
    int tap = t >> 1;
    return ((tap / 3) * WP + (tap % 3)) * CIN + (t & 1) * 64;
}
__device__ __forceinline__ int boffK(int t) {
    int tap = t >> 1;
    return tap * (COUT * CIN) + (t & 1) * 64;
}

// ---------- Main: 256x256, single-buffered LDS, 32x32x16 MFMA, 1-barrier phases ----------
// r12 with ONE change: the pre-MFMA barrier removed. Ordering audit: every stage
// issue at phase q targets a region whose last reads retired at a q-END barrier
// (chunk3 -> q3-end of t-1; Ac0' -> q0-end, incl. deferred B reads which
// lgkmcnt-retire before their wave's q0-end barrier); every ds_read consumes
// data whose DMA completion was published by an earlier q-end barrier (counted
// vmcnt ledger, per-wave, publish-at-barrier). The pre-MFMA barrier ordered
// nothing in this >=2-phase-prefetch schedule. Phases: [reads | stage | MFMA |
// counted-wait | barrier] -> 4 barriers/tile (was 8).

__global__ __launch_bounds__(512, 2) void conv_mfma8(const ushort_t* __restrict__ pad,
                                                     const ushort_t* __restrict__ wt,
                                                     const float* __restrict__ bias,
                                                     float* __restrict__ out) {
    __shared__ __align__(16) ushort_t lds[32768];   // 64 KiB: A[256][64] @0, B[256][64] @16384

    const int tid  = threadIdx.x;
    const int wid  = tid >> 6;
    const int lane = tid & 63;
    const int wm   = wid >> 2;       // 0..1 : 128-row band
    const int wn   = wid & 3;        // 0..3 : 64-col band
    const int bid  = blockIdx.x;
    const int bm   = (bid & 7) * 196 + (bid >> 3);   // XCD swizzle, 1568 % 8 == 0

    // ---- A-chunk staging geometry ----
    const int rb   = (tid & 255) >> 3;
    const int half = tid >> 8;
    const int lc   = (tid & 7) ^ (rb & 7) ^ ((rb >> 3) & 3);   // g(rb)

    const ushort_t* srcAc[4];
#pragma unroll
    for (int q = 0; q < 4; ++q) {
        int m  = bm * BM + half * 128 + q * 32 + rb;
        int n  = m / HW;
        int r  = m % HW;
        int oh = r / W;
        int ow = r % W;
        srcAc[q] = pad + ((size_t)((n * HP + oh) * WP + ow)) * CIN + lc * 8;
    }
    const ushort_t* srcB[4];
#pragma unroll
    for (int i = 0; i < 4; ++i)
        srcB[i] = wt + (size_t)(i * 64 + ((tid >> 3) & 63)) * CIN
                     + ((((tid & 7) ^ ((tid >> 3) & 7) ^ ((tid >> 6) & 3))) * 8);  // g(rw&31)

    const int awBase   = (wid >> 2) * 8192 + (wid & 3) * 512;
    const int dstSlotB = wid * 512;

#define STAGE_AC(q_, oA)                                                                            \
    __builtin_amdgcn_global_load_lds((gptr_t)(srcAc[q_] + (oA)),                                    \
                                     (lptr_t)&lds[(q_) * 2048 + awBase], 16, 0, 0);
#define STAGE_B1(j_, oB)                                                                            \
    __builtin_amdgcn_global_load_lds((gptr_t)(srcB[j_] + (oB)),                                     \
                                     (lptr_t)&lds[16384 + (j_) * 4096 + dstSlotB], 16, 0, 0);

    // ---- read-side constants (32x32 fragments; g-swizzled) ----
    const int aBase = (wm * 128 + (lane & 31)) * 64;            // + q*2048 per phase
    const int bBase = 16384 + (wn * 64 + (lane & 31)) * 64;     // + cb*2048 per colblock
    const int gr    = (lane & 7) ^ ((lane >> 3) & 3);           // g(lane&31)
    int cOff[4];
#pragma unroll
    for (int ksl = 0; ksl < 4; ++ksl)
        cOff[ksl] = ((ksl * 2 + (lane >> 5)) ^ gr) * 8;

    floatx16 acc[4][2];
#pragma unroll
    for (int i = 0; i < 4; ++i)
#pragma unroll
        for (int j = 0; j < 2; ++j) acc[i][j] = (floatx16)0.0f;

    // ---- prologue: A(0) chunks 0-2 + B(0) slices 0-3; full drain (once) ----
    {
        const int oA0 = aoffK(0);
        const int oB0 = boffK(0);
        STAGE_AC(0, oA0); STAGE_AC(1, oA0); STAGE_AC(2, oA0);
        STAGE_B1(0, oB0); STAGE_B1(1, oB0); STAGE_B1(2, oB0); STAGE_B1(3, oB0);
    }
    asm volatile("s_waitcnt vmcnt(0)" ::: "memory");
    __builtin_amdgcn_s_barrier();

    // ---- main loop (r12 schedule minus the pre-MFMA barrier) ----
    for (int t = 0; t < NT; ++t) {
        const int oAc = aoffK(t);
        const int oAn = aoffK(t + 1);
        const int oBn = boffK(t + 1);
        bf16x8 bfr[2][4];
#pragma unroll
        for (int q = 0; q < 4; ++q) {
            bf16x8 af[4];
#pragma unroll
            for (int ksl = 0; ksl < 4; ++ksl)
                af[ksl] = *reinterpret_cast<const bf16x8*>(&lds[aBase + q * 2048 + cOff[ksl]]);
            if (q == 0) {
#pragma unroll
                for (int ksl = 0; ksl < 4; ++ksl)   // cb=0 pre-MFMA; cb=1 deferred
                    bfr[0][ksl] = *reinterpret_cast<const bf16x8*>(&lds[bBase + cOff[ksl]]);
            }
            // staging issues (regions retired at the preceding q-end barrier)
            if (q == 0) { STAGE_AC(3, oAc); }
            if (q == 1 && t + 1 < NT) { STAGE_AC(0, oAn); STAGE_B1(0, oBn); STAGE_B1(1, oBn); }
            if (q == 2 && t + 1 < NT) { STAGE_AC(1, oAn); STAGE_B1(2, oBn); STAGE_B1(3, oBn); }
            if (q == 3 && t + 1 < NT) { STAGE_AC(2, oAn); }
            __builtin_amdgcn_s_setprio(1);
            if (q == 0) {
#pragma unroll
                for (int ksl = 0; ksl < 4; ++ksl)
                    acc[0][0] = __builtin_amdgcn_mfma_f32_32x32x16_bf16(af[ksl], bfr[0][ksl], acc[0][0], 0, 0, 0);
#pragma unroll
                for (int ksl = 0; ksl < 4; ++ksl)   // deferred cb=1 reads (q0-burst smoothing)
                    bfr[1][ksl] = *reinterpret_cast<const bf16x8*>(&lds[bBase + 2048 + cOff[ksl]]);
#pragma unroll
                for (int ksl = 0; ksl < 4; ++ksl)
                    acc[0][1] = __builtin_amdgcn_mfma_f32_32x32x16_bf16(af[ksl], bfr[1][ksl], acc[0][1], 0, 0, 0);
            } else {
#pragma unroll
                for (int ksl = 0; ksl < 4; ++ksl) {
                    acc[q][0] = __builtin_amdgcn_mfma_f32_32x32x16_bf16(af[ksl], bfr[0][ksl], acc[q][0], 0, 0, 0);
                    acc[q][1] = __builtin_amdgcn_mfma_f32_32x32x16_bf16(af[ksl], bfr[1][ksl], acc[q][1], 0, 0, 0);
                }
            }
            __builtin_amdgcn_s_setprio(0);
            // counted waits (r10 FIFO ledger, unchanged)
            if (q == 1) {
                if (t < NT - 1) { asm volatile("s_waitcnt vmcnt(4)" ::: "memory"); }
                else            { asm volatile("s_waitcnt vmcnt(1)" ::: "memory"); }
            }
            if (q == 2) {
                if (t < NT - 1) { asm volatile("s_waitcnt vmcnt(6)" ::: "memory"); }
                else            { asm volatile("s_waitcnt vmcnt(0)" ::: "memory"); }
            }
            if (q == 3) { asm volatile("s_waitcnt vmcnt(1)" ::: "memory"); }
            __builtin_amdgcn_s_barrier();
        }
    }

    // ---- epilogue: 32x32 C/D map col=lane&31, row=(reg&3)+8*(reg>>2)+4*(lane>>5) ----
    const int colL = wn * 64 + (lane & 31);
    const int rowL = bm * BM + wm * 128 + 4 * (lane >> 5);
    float bv[2];
#pragma unroll
    for (int cb = 0; cb < 2; ++cb) bv[cb] = bias[colL + cb * 32];
#pragma unroll
    for (int q = 0; q < 4; ++q)
#pragma unroll
        for (int cb = 0; cb < 2; ++cb)
#pragma unroll
            for (int reg = 0; reg < 16; ++reg) {
                int row = rowL + q * 32 + (reg & 3) + 8 * (reg >> 2);
                out[(size_t)row * COUT + colL + cb * 32] = acc[q][cb][reg] + bv[cb];
            }
#undef STAGE_AC
#undef STAGE_B1
}

extern "C" void kernel_launch(void* const* d_in, const int* in_sizes, int n_in,
                              void* d_out, int out_size, void* d_ws, size_t ws_size,
                              hipStream_t stream) {
    const float* input = (const float*)d_in[0];
    const float* kern  = (const float*)d_in[1];
    const float* bias  = (const float*)d_in[2];
    float* out         = (float*)d_out;

    ushort_t* pad = (ushort_t*)d_ws;                          // 106,463,232 B
    ushort_t* wt  = pad + (size_t)NIMG * HP * WP * CIN;       // + 589,824 B

    prepass_fused<<<PREPAD_BLOCKS + WTRANS_BLOCKS, 256, 0, stream>>>(input, kern, pad, wt);
    conv_mfma8<<<1568, 512, 0, stream>>>(pad, wt, bias, out); // 1568 = 401408/256, %8==0
}

// Round 14
// 342.806 us; speedup vs baseline: 1.0981x; 1.0198x over previous
//
#include <hip/hip_runtime.h>

typedef __attribute__((ext_vector_type(4)))  float   floatx4;
typedef __attribute__((ext_vector_type(16))) float   floatx16;
typedef __attribute__((ext_vector_type(8)))  __bf16  bf16x8;
typedef unsigned short ushort_t;
typedef __attribute__((ext_vector_type(8)))  ushort_t ushortx8;

typedef const unsigned int __attribute__((address_space(1)))* gptr_t;
typedef unsigned int __attribute__((address_space(3)))* lptr_t;

#define NIMG 32
#define H    112
#define W    112
#define CIN  128
#define COUT 256
#define HP   114
#define WP   114
#define HW   12544      // H*W; 12544 % 128 == 0 so every 128-row tile stays in one image

#define BM 128
#define BN 128
#define NT 18           // K = 3*3*128 = 1152 = 18*64
#define NBLK 6272       // 3136 M-tiles * 2 N-tiles; %8==0

#define PREPAD_BLOCKS 12996   // 32*114*114*8 / 256  (32B per thread)
#define WTRANS_BLOCKS 1152    // 3*3*256*128 / 256

// ---------- fp32 -> bf16 (round-to-nearest-even) ----------
__device__ __forceinline__ ushort_t f32_to_bf16(float f) {
    unsigned u = __float_as_uint(f);
    unsigned r = 0x7fffu + ((u >> 16) & 1u);
    return (ushort_t)((u + r) >> 16);
}

// ---------- Fused prepass (r8-verified, unchanged) ----------
__global__ __launch_bounds__(256) void prepass_fused(const float* __restrict__ in,
                                                     const float* __restrict__ k,
                                                     ushort_t* __restrict__ pad,
                                                     ushort_t* __restrict__ wt) {
    int bid = blockIdx.x;
    if (bid < PREPAD_BLOCKS) {
        int u    = bid * 256 + threadIdx.x;
        int ic16 = u & 7;
        int sp   = u >> 3;
        int iw   = sp % WP;
        int sp2  = sp / WP;
        int ih   = sp2 % HP;
        int n    = sp2 / HP;
        ushortx8 v0, v1;
        if (ih >= 1 && ih <= H && iw >= 1 && iw <= W) {
            const float* src = in + ((size_t)((n * H + (ih - 1)) * W + (iw - 1))) * CIN + ic16 * 16;
            floatx4 a = *reinterpret_cast<const floatx4*>(src);
            floatx4 b = *reinterpret_cast<const floatx4*>(src + 4);
            floatx4 c = *reinterpret_cast<const floatx4*>(src + 8);
            floatx4 d = *reinterpret_cast<const floatx4*>(src + 12);
#pragma unroll
            for (int j = 0; j < 4; ++j) {
                v0[j] = f32_to_bf16(a[j]); v0[4 + j] = f32_to_bf16(b[j]);
                v1[j] = f32_to_bf16(c[j]); v1[4 + j] = f32_to_bf16(d[j]);
            }
        } else {
#pragma unroll
            for (int j = 0; j < 8; ++j) { v0[j] = 0; v1[j] = 0; }
        }
        ushortx8* dst = reinterpret_cast<ushortx8*>(pad) + ((size_t)sp * 16 + ic16 * 2);
        dst[0] = v0;
        dst[1] = v1;
    } else {
        int t    = (bid - PREPAD_BLOCKS) * 256 + threadIdx.x;
        int ic   = t & 127;
        int oc   = (t >> 7) & 255;
        int khkw = t >> 15;
        wt[t] = f32_to_bf16(k[((size_t)(khkw * CIN + ic)) * COUT + oc]);
    }
}

// ---------- K-tile global offsets ----------
__device__ __forceinline__ int aoffK(int t) {
    int tap = t >> 1;
    return ((tap / 3) * WP + (tap % 3)) * CIN + (t & 1) * 64;
}
__device__ __forceinline__ int boffK(int t) {
    int tap = t >> 1;
    return tap * (COUT * CIN) + (t & 1) * 64;
}

// ---------- Main: 128x128 tile, 4 waves, 3 blocks/CU, 32x32x16 MFMA ----------
// Geometry = r1-verified 128² (2x2 waves of 64x64); techniques = r13-verified
// (g-swizzle, counted vmcnt, setprio, XCD swizzle, 1 barrier/phase).
// LDS 48KB (A dbuf 2x16KB + B single 16KB) -> 3 blocks/CU co-resident: one
// block's LDS-read burst overlaps other blocks' MFMA (cross-block pipelining).
// Per tile, 2 phases:
//  q0: read af0(4) + bfr0(4) -> MFMA acc[0][0]; read bfr1(4) -> MFMA acc[0][1];
//      stage A0',A2' -> A-buf^1; wait vmcnt(2|0) [forces A1,A3 of t]; barrier.
//  q1: read af1(4); stage B0'..B3' (B single-buf: all B reads retired at q0-end
//      barrier) + A1',A3'; MFMA acc[1][*]; wait vmcnt(2) [forces A0',A2',B';
//      leaves A1',A3' in flight]; barrier.
// Ledger audited incl. t=0 (prologue drains tile 0) and t=NT-1 (no staging;
// q0-end vmcnt(0) forces A1,A3). Never a full drain in steady state.

__global__ __launch_bounds__(256, 3) void conv_mfma4(const ushort_t* __restrict__ pad,
                                                     const ushort_t* __restrict__ wt,
                                                     const float* __restrict__ bias,
                                                     float* __restrict__ out) {
    __shared__ __align__(16) ushort_t lds[24576];   // 48 KiB: A dbuf 2x8192, B @16384

    const int tid  = threadIdx.x;
    const int wid  = tid >> 6;
    const int lane = tid & 63;
    const int wm   = wid >> 1;       // 0..1 : 64-row band
    const int wn   = wid & 1;        // 0..1 : 64-col band
    const int bid  = blockIdx.x;
    const int swz  = (bid & 7) * (NBLK / 8) + (bid >> 3);   // XCD swizzle, bijective
    const int mi   = swz >> 1;       // 0..3135
    const int ni   = swz & 1;        // 0..1

    // ---- staging geometry: slice s = 32 rows x 64 k = 4KB = 256 thr x 16B ----
    const int trow = tid >> 3;                               // 0..31
    const int lc   = (tid & 7) ^ (trow & 7) ^ ((trow >> 3) & 3);   // g(trow)

    const ushort_t* srcA[4];
    const ushort_t* srcB[4];
#pragma unroll
    for (int s = 0; s < 4; ++s) {
        int m  = mi * BM + s * 32 + trow;
        int n  = m / HW;
        int r  = m % HW;
        int oh = r / W;
        int ow = r % W;
        srcA[s] = pad + ((size_t)((n * HP + oh) * WP + ow)) * CIN + lc * 8;
        srcB[s] = wt + (size_t)(ni * BN + s * 32 + trow) * CIN + lc * 8;
    }
    const int dstSlot = wid * 512;   // ushort offset within a 2048-ushort slice

#define STAGE_A(par, s_, oA)                                                                        \
    __builtin_amdgcn_global_load_lds((gptr_t)(srcA[s_] + (oA)),                                     \
                                     (lptr_t)&lds[(par) * 8192 + (s_) * 2048 + dstSlot], 16, 0, 0);
#define STAGE_B(s_, oB)                                                                             \
    __builtin_amdgcn_global_load_lds((gptr_t)(srcB[s_] + (oB)),                                     \
                                     (lptr_t)&lds[16384 + (s_) * 2048 + dstSlot], 16, 0, 0);

    // ---- read-side constants (32x32 fragments; g-swizzled) ----
    const int aBase = (wm * 64 + (lane & 31)) * 64;             // + par*8192 + rf*2048
    const int bBase = 16384 + (wn * 64 + (lane & 31)) * 64;     // + cb*2048
    const int gr    = (lane & 7) ^ ((lane >> 3) & 3);           // g(lane&31)
    int cOff[4];
#pragma unroll
    for (int ksl = 0; ksl < 4; ++ksl)
        cOff[ksl] = ((ksl * 2 + (lane >> 5)) ^ gr) * 8;

    floatx16 acc[2][2];
#pragma unroll
    for (int i = 0; i < 2; ++i)
#pragma unroll
        for (int j = 0; j < 2; ++j) acc[i][j] = (floatx16)0.0f;

    // ---- prologue: A(0) slices 0-3 + B(0) slices 0-3; full drain (once) ----
    {
        const int oA0 = aoffK(0);
        const int oB0 = boffK(0);
        STAGE_A(0, 0, oA0); STAGE_A(0, 1, oA0); STAGE_A(0, 2, oA0); STAGE_A(0, 3, oA0);
        STAGE_B(0, oB0); STAGE_B(1, oB0); STAGE_B(2, oB0); STAGE_B(3, oB0);
    }
    asm volatile("s_waitcnt vmcnt(0)" ::: "memory");
    __builtin_amdgcn_s_barrier();

    // ---- main loop ----
    for (int t = 0; t < NT; ++t) {
        const int par  = t & 1;
        const int parn = par ^ 1;
        const int oAn  = aoffK(t + 1);   // guarded
        const int oBn  = boffK(t + 1);   // guarded
        const int aB   = par * 8192 + aBase;
        bf16x8 af[4], bfr0[4], bfr1[4];

        // ======== phase 0 : acc[0][*] ========
#pragma unroll
        for (int ksl = 0; ksl < 4; ++ksl) {
            af[ksl]   = *reinterpret_cast<const bf16x8*>(&lds[aB + cOff[ksl]]);
            bfr0[ksl] = *reinterpret_cast<const bf16x8*>(&lds[bBase + cOff[ksl]]);
        }
        if (t + 1 < NT) { STAGE_A(parn, 0, oAn); STAGE_A(parn, 2, oAn); }
        __builtin_amdgcn_s_setprio(1);
#pragma unroll
        for (int ksl = 0; ksl < 4; ++ksl)
            acc[0][0] = __builtin_amdgcn_mfma_f32_32x32x16_bf16(af[ksl], bfr0[ksl], acc[0][0], 0, 0, 0);
#pragma unroll
        for (int ksl = 0; ksl < 4; ++ksl)   // bfr1 reads mid-cluster (burst smoothing)
            bfr1[ksl] = *reinterpret_cast<const bf16x8*>(&lds[bBase + 2048 + cOff[ksl]]);
#pragma unroll
        for (int ksl = 0; ksl < 4; ++ksl)
            acc[0][1] = __builtin_amdgcn_mfma_f32_32x32x16_bf16(af[ksl], bfr1[ksl], acc[0][1], 0, 0, 0);
        __builtin_amdgcn_s_setprio(0);
        if (t + 1 < NT) { asm volatile("s_waitcnt vmcnt(2)" ::: "memory"); }
        else            { asm volatile("s_waitcnt vmcnt(0)" ::: "memory"); }
        __builtin_amdgcn_s_barrier();

        // ======== phase 1 : acc[1][*] ========
#pragma unroll
        for (int ksl = 0; ksl < 4; ++ksl)
            af[ksl] = *reinterpret_cast<const bf16x8*>(&lds[aB + 2048 + cOff[ksl]]);
        if (t + 1 < NT) {
            STAGE_B(0, oBn); STAGE_B(1, oBn); STAGE_B(2, oBn); STAGE_B(3, oBn);
            STAGE_A(parn, 1, oAn); STAGE_A(parn, 3, oAn);
        }
        __builtin_amdgcn_s_setprio(1);
#pragma unroll
        for (int ksl = 0; ksl < 4; ++ksl) {
            acc[1][0] = __builtin_amdgcn_mfma_f32_32x32x16_bf16(af[ksl], bfr0[ksl], acc[1][0], 0, 0, 0);
            acc[1][1] = __builtin_amdgcn_mfma_f32_32x32x16_bf16(af[ksl], bfr1[ksl], acc[1][1], 0, 0, 0);
        }
        __builtin_amdgcn_s_setprio(0);
        if (t + 1 < NT) { asm volatile("s_waitcnt vmcnt(2)" ::: "memory"); }
        __builtin_amdgcn_s_barrier();
    }

    // ---- epilogue: 32x32 C/D map col=lane&31, row=(reg&3)+8*(reg>>2)+4*(lane>>5) ----
    const int colL = ni * BN + wn * 64 + (lane & 31);
    const int rowL = mi * BM + wm * 64 + 4 * (lane >> 5);
    float bv[2];
#pragma unroll
    for (int cb = 0; cb < 2; ++cb) bv[cb] = bias[colL + cb * 32];
#pragma unroll
    for (int rf = 0; rf < 2; ++rf)
#pragma unroll
        for (int cb = 0; cb < 2; ++cb)
#pragma unroll
            for (int reg = 0; reg < 16; ++reg) {
                int row = rowL + rf * 32 + (reg & 3) + 8 * (reg >> 2);
                out[(size_t)row * COUT + colL + cb * 32] = acc[rf][cb][reg] + bv[cb];
            }
#undef STAGE_A
#undef STAGE_B
}

extern "C" void kernel_launch(void* const* d_in, const int* in_sizes, int n_in,
                              void* d_out, int out_size, void* d_ws, size_t ws_size,
                              hipStream_t stream) {
    const float* input = (const float*)d_in[0];
    const float* kern  = (const float*)d_in[1];
    const float* bias  = (const float*)d_in[2];
    float* out         = (float*)d_out;

    ushort_t* pad = (ushort_t*)d_ws;                          // 106,463,232 B
    ushort_t* wt  = pad + (size_t)NIMG * HP * WP * CIN;       // + 589,824 B

    prepass_fused<<<PREPAD_BLOCKS + WTRANS_BLOCKS, 256, 0, stream>>>(input, kern, pad, wt);
    conv_mfma4<<<NBLK, 256, 0, stream>>>(pad, wt, bias, out); // 6272 = 3136 M x 2 N
}